// Round 18
// baseline (430.622 us; speedup 1.0000x reference)
//
#include <hip/hip_runtime.h>
#include <math.h>

#define N_FILT   80
#define FILT_DIM 251
#define KPAD     256
#define SIG_LEN  32000
#define OUT_LEN  31750
#define BATCH    32
#define TPB      320       // 5 waves: wave w owns filter-block fb = w

#define STRIP    512       // t-range per block (64 strips -> 2048 blocks)
#define NREP     8         // shifted replicas -> every window is 16B aligned
#define LROW     388       // dwords per replica: %4==0 (16B align), /4 odd (bank spread); max frag dword 379
#define OBS2     36        // ob row stride (dwords) for 32-col flush groups

#define TWO_PI_F 6.28318530717958647692f

typedef __attribute__((ext_vector_type(8))) short    short8;   // raw 16B frag
typedef __attribute__((ext_vector_type(8))) _Float16 half8;    // fp16 A/B frag
typedef __attribute__((ext_vector_type(4))) float    float4v;  // C/D frag
typedef __attribute__((ext_vector_type(2))) float    float2v;  // store pair

// ---------------------------------------------------------------------------
// Kernel 1: build 80 sinc band-pass filters directly in fp16.
// ---------------------------------------------------------------------------
__global__ __launch_bounds__(256) void build_filters_kernel(
    const float* __restrict__ b1, const float* __restrict__ band,
    unsigned short* __restrict__ fh)
{
    const int f = blockIdx.x;
    const int i = threadIdx.x;

    const float MINF = 50.0f / 16000.0f;
    const float fb = fabsf(b1[f]) + MINF;
    const float fe = fb + fabsf(band[f]) + MINF;

    float v = 0.0f;
    if (i < FILT_DIM) {
        int m = i - 125; m = (m < 0) ? -m : m;
        if (m == 0) v = 2.0f * fe - 2.0f * fb;
        else {
            float a1 = TWO_PI_F * fb * (float)m;
            float a2 = TWO_PI_F * fe * (float)m;
            v = 2.0f * fe * (sinf(a2) / a2) - 2.0f * fb * (sinf(a1) / a1);
        }
    }

    __shared__ float red[256];
    red[i] = (i < FILT_DIM) ? v : -INFINITY;
    __syncthreads();
    #pragma unroll
    for (int s = 128; s > 0; s >>= 1) {
        if (i < s) red[i] = fmaxf(red[i], red[i + s]);
        __syncthreads();
    }
    const float mx = red[0];

    const float w   = 0.54f - 0.46f * cosf(TWO_PI_F * (float)i / 250.0f);
    const float val = (i < FILT_DIM) ? (v / mx) * w : 0.0f;
    const _Float16 h = (_Float16)val;                 // RNE v_cvt_f16_f32
    fh[f * KPAD + i] = __builtin_bit_cast(unsigned short, h);  // pad rows = 0
}

// ---------------------------------------------------------------------------
// Kernel 2 (R17): conv as MFMA GEMM (fp16) -- R13 body with STRIP 1024->512.
//   R16 diagnostic readout: WRITE = ~350 MB/rep (NO RMW amplification);
//   steady-state write BW for this pattern = 4.8-5.4 TB/s; exposed
//   prologue/ramp P = 13-15 us.  Single-pass 85 us = 70 us steady + P +
//   un-overlapped tail: at grid 1024 the WHOLE grid is resident (5
//   blocks/CU), so all blocks stage simultaneously at t=0 and drain
//   together -- zero pipelining rounds.
//   Fix: STRIP=512 -> 2048 blocks = ~8 blocks/CU of work with 5 resident:
//   later blocks' staging overlaps earlier blocks' stores; per-block
//   staging latency before first store halves.  Everything else is the
//   proven R13 configuration (5 waves, wave w owns fb=w, ONE barrier,
//   wave-private ob, 2-tile flush groups, (320,7) bounds, XCD swizzle).
// ---------------------------------------------------------------------------
__global__ __launch_bounds__(TPB, 7) void sinc_mfma_kernel(
    const float* __restrict__ x,
    const unsigned short* __restrict__ fh,
    float* __restrict__ out)
{
    __shared__ __align__(16) unsigned xf[NREP * LROW];     // 12.4 KB
    __shared__ __align__(16) float    ob[5][16 * OBS2];    // 11.5 KB

    const int tid = threadIdx.x;
    // XCD swizzle: 2048 blocks, raw%8 = XCD -> each XCD owns 256 contiguous
    // (strip,n) tasks = 4 complete batches.  2048 % 8 == 0 -> bijective.
    const unsigned raw = blockIdx.x;
    const unsigned swz = (raw & 7u) * 256u + (raw >> 3);
    const int strip = (int)(swz & 63u);
    const int n     = (int)(swz >> 6);
    const int e0    = strip * STRIP;
    const float* xp = x + (size_t)n * SIG_LEN;

    // ---- stage x: fp16, 8 shifted replicas (replica r, dword d = elems 2d+r,2d+r+1)
    for (int d = tid; d < LROW; d += TPB) {
        const int g = e0 + 2 * d;
        float v0, v1, v2;
        if (g + 2 < SIG_LEN) {
            float2 p = *(const float2*)(xp + g);
            v0 = p.x; v1 = p.y; v2 = xp[g + 2];
        } else {
            v0 = (g     < SIG_LEN) ? xp[g]     : 0.0f;
            v1 = (g + 1 < SIG_LEN) ? xp[g + 1] : 0.0f;
            v2 = (g + 2 < SIG_LEN) ? xp[g + 2] : 0.0f;
        }
        const _Float16 h0 = (_Float16)v0, h1 = (_Float16)v1, h2 = (_Float16)v2;
        union { _Float16 h[2]; unsigned u; } pe, po;
        pe.h[0] = h0; pe.h[1] = h1;          // elems 2d, 2d+1
        po.h[0] = h1; po.h[1] = h2;          // elems 2d+1, 2d+2
        xf[0 * LROW + d] = pe.u;                                  // r=0
        xf[1 * LROW + d] = po.u;                                  // r=1
        if (d >= 1) { xf[2 * LROW + d - 1] = pe.u;                // r=2
                      xf[3 * LROW + d - 1] = po.u; }              // r=3
        if (d >= 2) { xf[4 * LROW + d - 2] = pe.u;                // r=4
                      xf[5 * LROW + d - 2] = po.u; }              // r=5
        if (d >= 3) { xf[6 * LROW + d - 3] = pe.u;                // r=6
                      xf[7 * LROW + d - 3] = po.u; }              // r=7
    }

    // ---- A fragments: wave w reads its 16 filters (fb = w) ------------------
    const int lane = tid & 63;
    const int w    = tid >> 6;        // wave id == filter-block
    const int m    = lane & 15;       // B-col (t offset) / C-col
    const int q    = lane >> 4;       // quad: k = q*8+j ; C-row = q*4+reg
    short8 Ah[8];
    {
        const unsigned short* ph = fh + (w * 16 + m) * KPAD + q * 8;
        #pragma unroll
        for (int kb = 0; kb < 8; ++kb)
            Ah[kb] = *(const short8*)(ph + kb * 32);
    }
    __syncthreads();                  // the ONLY barrier

    // ---- main loop: 32 t-tiles in 16 groups of 2, flush per group ----------
    // element start s = 16tt + m + 8q + 32kb ; replica r = m&7
    // frag dword offset = base + 8*tt + 16*kb  (16B-aligned, balanced
    // 8 lanes per 16B bank group per b128 -> conflict-free)
    const int r = m & 7;
    const unsigned base = (unsigned)(r * LROW + 4 * (m >> 3) + 4 * q);

    float* const obw  = &ob[w][0];
    const int    cp   = 2 * (lane & 15);       // flush: group-local col pair
    const int    rr0  = lane >> 4;             // flush: row 0..3 (+4j)
    const size_t row0 = ((size_t)n * N_FILT + w * 16) * OUT_LEN;

    for (int gp = 0; gp < 16; ++gp) {          // 16 groups of 32 cols
        #pragma unroll
        for (int tl = 0; tl < 2; ++tl) {
            const int tt = gp * 2 + tl;
            float4v a0 = {0.f,0.f,0.f,0.f}, a1 = {0.f,0.f,0.f,0.f};
            const unsigned o0 = base + 8u * (unsigned)tt;
            #pragma unroll
            for (int kk = 0; kk < 4; ++kk) {   // kb = 2kk (a0), 2kk+1 (a1)
                a0 = __builtin_amdgcn_mfma_f32_16x16x32_f16(
                         __builtin_bit_cast(half8, Ah[2*kk]),
                         __builtin_bit_cast(half8, *(const uint4*)(&xf[o0 + 32*kk])),
                         a0, 0, 0, 0);
                a1 = __builtin_amdgcn_mfma_f32_16x16x32_f16(
                         __builtin_bit_cast(half8, Ah[2*kk+1]),
                         __builtin_bit_cast(half8, *(const uint4*)(&xf[o0 + 32*kk + 16])),
                         a1, 0, 0, 0);
            }
            const int oc = tl * 16 + m;        // group-local col
            #pragma unroll
            for (int rg = 0; rg < 4; ++rg)
                obw[(q * 4 + rg) * OBS2 + oc] = a0[rg] + a1[rg];
        }

        // flush group: 4 float2 stores (4 rows x 128 B each), conflict-free
        const int t0 = e0 + gp * 32 + cp;      // even; OUT_LEN even
        if (t0 + 1 < OUT_LEN) {
            #pragma unroll
            for (int j = 0; j < 4; ++j) {
                const int row = j * 4 + rr0;
                const float2v v = *(const float2v*)(&obw[row * OBS2 + cp]);
                *(float2v*)(out + row0 + (size_t)row * OUT_LEN + t0) = v;
            }
        }
    }
}

// ---------------------------------------------------------------------------
extern "C" void kernel_launch(void* const* d_in, const int* in_sizes, int n_in,
                              void* d_out, int out_size, void* d_ws, size_t ws_size,
                              hipStream_t stream)
{
    const float* x    = (const float*)d_in[0];
    const float* b1   = (const float*)d_in[1];
    const float* band = (const float*)d_in[2];
    float* outp = (float*)d_out;

    unsigned short* fh = (unsigned short*)d_ws;          // 80*256*2 B = 40 KB

    build_filters_kernel<<<dim3(N_FILT), dim3(256), 0, stream>>>(b1, band, fh);

    dim3 grid(2048);                                     // 64 strips x 32 n
    sinc_mfma_kernel<<<grid, dim3(TPB), 0, stream>>>(x, fh, outp);
}

// Round 19
// 206.198 us; speedup vs baseline: 2.0884x; 2.0884x over previous
//
#include <hip/hip_runtime.h>
#include <math.h>

#define N_FILT   80
#define FILT_DIM 251
#define SIG_LEN  32000
#define OUT_LEN  31750
#define BATCH    32
#define TPB      320       // 5 waves: wave w owns filter-block fb = w

#define STRIP    1024      // t-range per block
#define NREP     8         // shifted replicas -> every window is 16B aligned
#define LROW     644       // dwords per replica: %4==0 (16B align), /4 odd (bank spread)
#define OBS2     36        // ob row stride (dwords) for 32-col flush groups

#define TWO_PI_F 6.28318530717958647692f

typedef __attribute__((ext_vector_type(8))) short    short8;   // raw 16B frag
typedef __attribute__((ext_vector_type(8))) _Float16 half8;    // fp16 A/B frag
typedef __attribute__((ext_vector_type(4))) float    float4v;  // C/D frag
typedef __attribute__((ext_vector_type(2))) float    float2v;  // store pair

// ---------------------------------------------------------------------------
// Single fused kernel (R18): conv as MFMA GEMM (fp16) -- R13 body (proven
// 85.0 us; R16 x3 diagnostic on this body: clean writes ~350 MB/rep at
// 4.8-5.2 TB/s) with the filter build FUSED in:
//   - lane (m,q)'s A-fragments need exactly taps i = 32kb+8q+j of filter
//     16w+m, and the 4 q-lanes jointly cover all 251 taps.  So each lane
//     computes its own 64 taps straight into Ah registers (128 sinf, pure
//     VALU, overlaps the x-staging memory phase across 25 resident waves).
//   - per-filter max: 2x shfl_xor across q.  Normalization 1/mx moves to
//     the epilogue as a per-row fp32 scale (4 shfl'd regs) -- single pass,
//     no LDS, no tap redistribution, no build kernel, no fh traffic.
//   Removes the serialized build_filters_kernel launch + fh prologue loads
//   (~6-10 us of serial head).  Main loop / staging / flush: R13 verbatim.
// ---------------------------------------------------------------------------
__global__ __launch_bounds__(TPB, 7) void sinc_mfma_kernel(
    const float* __restrict__ x,
    const float* __restrict__ b1,
    const float* __restrict__ band,
    float* __restrict__ out)
{
    __shared__ __align__(16) unsigned xf[NREP * LROW];     // 20.6 KB
    __shared__ __align__(16) float    ob[5][16 * OBS2];    // 11.5 KB

    const int tid = threadIdx.x;
    // XCD swizzle: raw%8 = XCD -> each XCD owns 128 contiguous (strip,n)
    // blocks = 4 complete batches.  1024 % 8 == 0 -> bijective.
    const unsigned raw = blockIdx.x;
    const unsigned swz = (raw & 7u) * 128u + (raw >> 3);
    const int strip = (int)(swz & 31u);
    const int n     = (int)(swz >> 5);
    const int e0    = strip * STRIP;
    const float* xp = x + (size_t)n * SIG_LEN;

    // ---- stage x: fp16, 8 shifted replicas (replica r, dword d = elems 2d+r,2d+r+1)
    for (int d = tid; d < LROW; d += TPB) {
        const int g = e0 + 2 * d;
        float v0, v1, v2;
        if (g + 2 < SIG_LEN) {
            float2 p = *(const float2*)(xp + g);
            v0 = p.x; v1 = p.y; v2 = xp[g + 2];
        } else {
            v0 = (g     < SIG_LEN) ? xp[g]     : 0.0f;
            v1 = (g + 1 < SIG_LEN) ? xp[g + 1] : 0.0f;
            v2 = (g + 2 < SIG_LEN) ? xp[g + 2] : 0.0f;
        }
        const _Float16 h0 = (_Float16)v0, h1 = (_Float16)v1, h2 = (_Float16)v2;
        union { _Float16 h[2]; unsigned u; } pe, po;
        pe.h[0] = h0; pe.h[1] = h1;          // elems 2d, 2d+1
        po.h[0] = h1; po.h[1] = h2;          // elems 2d+1, 2d+2
        xf[0 * LROW + d] = pe.u;                                  // r=0
        xf[1 * LROW + d] = po.u;                                  // r=1
        if (d >= 1) { xf[2 * LROW + d - 1] = pe.u;                // r=2
                      xf[3 * LROW + d - 1] = po.u; }              // r=3
        if (d >= 2) { xf[4 * LROW + d - 2] = pe.u;                // r=4
                      xf[5 * LROW + d - 2] = po.u; }              // r=5
        if (d >= 3) { xf[6 * LROW + d - 3] = pe.u;                // r=6
                      xf[7 * LROW + d - 3] = po.u; }              // r=7
    }

    const int lane = tid & 63;
    const int w    = tid >> 6;        // wave id == filter-block
    const int m    = lane & 15;       // A-row (f) / C-col (t)
    const int q    = lane >> 4;       // quad: k = q*8+j ; C-row = q*4+reg

    // ---- fused filter build: lane computes ITS OWN 64 taps into Ah ---------
    const int fg = w * 16 + m;                         // global filter row
    const float MINF = 50.0f / 16000.0f;
    const float fbv = fabsf(b1[fg]) + MINF;
    const float fev = fbv + fabsf(band[fg]) + MINF;
    float mx = -INFINITY;
    short8 Ah[8];
    #pragma unroll
    for (int kb = 0; kb < 8; ++kb) {
        union { unsigned short u[8]; short8 s; } pk;
        #pragma unroll
        for (int j = 0; j < 8; ++j) {
            const int i = 32 * kb + 8 * q + j;         // tap index
            if (i < FILT_DIM) {
                int mm = i - 125; mm = (mm < 0) ? -mm : mm;
                float v;
                if (mm == 0) v = 2.0f * fev - 2.0f * fbv;
                else {
                    const float a1 = TWO_PI_F * fbv * (float)mm;
                    const float a2 = TWO_PI_F * fev * (float)mm;
                    v = 2.0f * fev * (sinf(a2) / a2)
                      - 2.0f * fbv * (sinf(a1) / a1);
                }
                mx = fmaxf(mx, v);                     // max of RAW bandpass
                const float wdw =
                    0.54f - 0.46f * cosf(TWO_PI_F * (float)i / 250.0f);
                const _Float16 hv = (_Float16)(v * wdw);
                pk.u[j] = __builtin_bit_cast(unsigned short, hv);
            } else {
                pk.u[j] = 0;                           // k-pad zeros
            }
        }
        Ah[kb] = pk.s;
    }
    // cross-q max (4 lanes of same m jointly cover taps 0..250)
    mx = fmaxf(mx, __shfl_xor(mx, 16));
    mx = fmaxf(mx, __shfl_xor(mx, 32));
    const float rs = 1.0f / mx;
    // epilogue scales: C-row rg of this lane is filter q*4+rg -> rs from
    // lane q*4+rg (q'=0 lanes hold m = lane id)
    float rsv[4];
    #pragma unroll
    for (int j = 0; j < 4; ++j)
        rsv[j] = __shfl(rs, q * 4 + j);

    __syncthreads();                  // the ONLY barrier (xf ready)

    // ---- main loop: 64 t-tiles in 32 groups of 2, flush per group ----------
    // element start s = 16tt + m + 8q + 32kb ; replica r = m&7
    // frag dword offset = base + 8*tt + 16*kb  (16B-aligned, balanced
    // 8 lanes per 16B bank group per b128 -> conflict-free)
    const int r = m & 7;
    const unsigned base = (unsigned)(r * LROW + 4 * (m >> 3) + 4 * q);

    float* const obw  = &ob[w][0];
    const int    cp   = 2 * (lane & 15);       // flush: group-local col pair
    const int    rr0  = lane >> 4;             // flush: row 0..3 (+4j)
    const size_t row0 = ((size_t)n * N_FILT + w * 16) * OUT_LEN;

    for (int gp = 0; gp < 32; ++gp) {          // 32 groups of 32 cols
        #pragma unroll
        for (int tl = 0; tl < 2; ++tl) {
            const int tt = gp * 2 + tl;
            float4v a0 = {0.f,0.f,0.f,0.f}, a1 = {0.f,0.f,0.f,0.f};
            const unsigned o0 = base + 8u * (unsigned)tt;
            #pragma unroll
            for (int kk = 0; kk < 4; ++kk) {   // kb = 2kk (a0), 2kk+1 (a1)
                a0 = __builtin_amdgcn_mfma_f32_16x16x32_f16(
                         __builtin_bit_cast(half8, Ah[2*kk]),
                         __builtin_bit_cast(half8, *(const uint4*)(&xf[o0 + 32*kk])),
                         a0, 0, 0, 0);
                a1 = __builtin_amdgcn_mfma_f32_16x16x32_f16(
                         __builtin_bit_cast(half8, Ah[2*kk+1]),
                         __builtin_bit_cast(half8, *(const uint4*)(&xf[o0 + 32*kk + 16])),
                         a1, 0, 0, 0);
            }
            const int oc = tl * 16 + m;        // group-local col
            #pragma unroll
            for (int rg = 0; rg < 4; ++rg)     // normalization folded here
                obw[(q * 4 + rg) * OBS2 + oc] = (a0[rg] + a1[rg]) * rsv[rg];
        }

        // flush group: 4 float2 stores (4 rows x 128 B each), conflict-free
        const int t0 = e0 + gp * 32 + cp;      // even; OUT_LEN even
        if (t0 + 1 < OUT_LEN) {
            #pragma unroll
            for (int j = 0; j < 4; ++j) {
                const int row = j * 4 + rr0;
                const float2v v = *(const float2v*)(&obw[row * OBS2 + cp]);
                *(float2v*)(out + row0 + (size_t)row * OUT_LEN + t0) = v;
            }
        }
    }
}

// ---------------------------------------------------------------------------
extern "C" void kernel_launch(void* const* d_in, const int* in_sizes, int n_in,
                              void* d_out, int out_size, void* d_ws, size_t ws_size,
                              hipStream_t stream)
{
    const float* x    = (const float*)d_in[0];
    const float* b1   = (const float*)d_in[1];
    const float* band = (const float*)d_in[2];
    float* outp = (float*)d_out;

    (void)d_ws; (void)ws_size;                           // no workspace needed

    dim3 grid(1024);                                     // 32 strips x 32 n
    sinc_mfma_kernel<<<grid, dim3(TPB), 0, stream>>>(x, b1, band, outp);
}

// Round 20
// 84.605 us; speedup vs baseline: 5.0898x; 2.4372x over previous
//
#include <hip/hip_runtime.h>
#include <math.h>

#define N_FILT   80
#define FILT_DIM 251
#define KPAD     256
#define SIG_LEN  32000
#define OUT_LEN  31750
#define BATCH    32
#define TPB      320       // 5 waves: wave w owns filter-block fb = w

#define STRIP    1024      // t-range per block
#define NREP     8         // shifted replicas -> every window is 16B aligned
#define LROW     644       // dwords per replica: %4==0 (16B align), /4 odd (bank spread)
#define OBS2     36        // ob row stride (dwords) for 32-col flush groups

#define TWO_PI_F 6.28318530717958647692f

typedef __attribute__((ext_vector_type(8))) short    short8;   // raw 16B frag
typedef __attribute__((ext_vector_type(8))) _Float16 half8;    // fp16 A/B frag
typedef __attribute__((ext_vector_type(4))) float    float4v;  // C/D frag
typedef __attribute__((ext_vector_type(2))) float    float2v;  // store pair

// ---------------------------------------------------------------------------
// Kernel 1: build 80 sinc band-pass filters directly in fp16.
// (Separate kernel on purpose: R18 proved fusing this into the conv kernel
//  spills Ah to scratch -- the conv inner loop lives at a VGPR cliff.)
// ---------------------------------------------------------------------------
__global__ __launch_bounds__(256) void build_filters_kernel(
    const float* __restrict__ b1, const float* __restrict__ band,
    unsigned short* __restrict__ fh)
{
    const int f = blockIdx.x;
    const int i = threadIdx.x;

    const float MINF = 50.0f / 16000.0f;
    const float fb = fabsf(b1[f]) + MINF;
    const float fe = fb + fabsf(band[f]) + MINF;

    float v = 0.0f;
    if (i < FILT_DIM) {
        int m = i - 125; m = (m < 0) ? -m : m;
        if (m == 0) v = 2.0f * fe - 2.0f * fb;
        else {
            float a1 = TWO_PI_F * fb * (float)m;
            float a2 = TWO_PI_F * fe * (float)m;
            v = 2.0f * fe * (sinf(a2) / a2) - 2.0f * fb * (sinf(a1) / a1);
        }
    }

    __shared__ float red[256];
    red[i] = (i < FILT_DIM) ? v : -INFINITY;
    __syncthreads();
    #pragma unroll
    for (int s = 128; s > 0; s >>= 1) {
        if (i < s) red[i] = fmaxf(red[i], red[i + s]);
        __syncthreads();
    }
    const float mx = red[0];

    const float w   = 0.54f - 0.46f * cosf(TWO_PI_F * (float)i / 250.0f);
    const float val = (i < FILT_DIM) ? (v / mx) * w : 0.0f;
    const _Float16 h = (_Float16)val;                 // RNE v_cvt_f16_f32
    fh[f * KPAD + i] = __builtin_bit_cast(unsigned short, h);  // pad rows = 0
}

// ---------------------------------------------------------------------------
// Kernel 2 (R13 config, proven 85.0 us): conv as MFMA GEMM (fp16).
//   C[f,t] = sum_k F[f,k] * x[t+k]
//   5 waves, wave w owns filter-block fb=w; x staged once (8 shifted fp16
//   replicas, conflict-free ds_read_b128); ONE barrier; 2-tile groups with
//   wave-private ob gather + 4x float2 flush (128 B/row-event); no vmcnt
//   drains; XCD-swizzled grid; __launch_bounds__(320,7) -> 5 blocks/CU.
//   Measured floor context (R16 x3 diagnostic): pattern-specific steady
//   write BW ~5.0-5.4 TB/s, exposed prologue ~13-15 us -> ~81-83 us floor.
// ---------------------------------------------------------------------------
__global__ __launch_bounds__(TPB, 7) void sinc_mfma_kernel(
    const float* __restrict__ x,
    const unsigned short* __restrict__ fh,
    float* __restrict__ out)
{
    __shared__ __align__(16) unsigned xf[NREP * LROW];     // 20.6 KB
    __shared__ __align__(16) float    ob[5][16 * OBS2];    // 11.5 KB

    const int tid = threadIdx.x;
    // XCD swizzle: raw%8 = XCD -> each XCD owns 128 contiguous (strip,n)
    // blocks = 4 complete batches.  1024 % 8 == 0 -> bijective.
    const unsigned raw = blockIdx.x;
    const unsigned swz = (raw & 7u) * 128u + (raw >> 3);
    const int strip = (int)(swz & 31u);
    const int n     = (int)(swz >> 5);
    const int e0    = strip * STRIP;
    const float* xp = x + (size_t)n * SIG_LEN;

    // ---- stage x: fp16, 8 shifted replicas (replica r, dword d = elems 2d+r,2d+r+1)
    for (int d = tid; d < LROW; d += TPB) {
        const int g = e0 + 2 * d;
        float v0, v1, v2;
        if (g + 2 < SIG_LEN) {
            float2 p = *(const float2*)(xp + g);
            v0 = p.x; v1 = p.y; v2 = xp[g + 2];
        } else {
            v0 = (g     < SIG_LEN) ? xp[g]     : 0.0f;
            v1 = (g + 1 < SIG_LEN) ? xp[g + 1] : 0.0f;
            v2 = (g + 2 < SIG_LEN) ? xp[g + 2] : 0.0f;
        }
        const _Float16 h0 = (_Float16)v0, h1 = (_Float16)v1, h2 = (_Float16)v2;
        union { _Float16 h[2]; unsigned u; } pe, po;
        pe.h[0] = h0; pe.h[1] = h1;          // elems 2d, 2d+1
        po.h[0] = h1; po.h[1] = h2;          // elems 2d+1, 2d+2
        xf[0 * LROW + d] = pe.u;                                  // r=0
        xf[1 * LROW + d] = po.u;                                  // r=1
        if (d >= 1) { xf[2 * LROW + d - 1] = pe.u;                // r=2
                      xf[3 * LROW + d - 1] = po.u; }              // r=3
        if (d >= 2) { xf[4 * LROW + d - 2] = pe.u;                // r=4
                      xf[5 * LROW + d - 2] = po.u; }              // r=5
        if (d >= 3) { xf[6 * LROW + d - 3] = pe.u;                // r=6
                      xf[7 * LROW + d - 3] = po.u; }              // r=7
    }

    // ---- A fragments: wave w reads its 16 filters (fb = w) ------------------
    const int lane = tid & 63;
    const int w    = tid >> 6;        // wave id == filter-block
    const int m    = lane & 15;       // B-col (t offset) / C-col
    const int q    = lane >> 4;       // quad: k = q*8+j ; C-row = q*4+reg
    short8 Ah[8];
    {
        const unsigned short* ph = fh + (w * 16 + m) * KPAD + q * 8;
        #pragma unroll
        for (int kb = 0; kb < 8; ++kb)
            Ah[kb] = *(const short8*)(ph + kb * 32);
    }
    __syncthreads();                  // the ONLY barrier

    // ---- main loop: 64 t-tiles in 32 groups of 2, flush per group ----------
    // element start s = 16tt + m + 8q + 32kb ; replica r = m&7
    // frag dword offset = base + 8*tt + 16*kb  (16B-aligned, balanced
    // 8 lanes per 16B bank group per b128 -> conflict-free)
    const int r = m & 7;
    const unsigned base = (unsigned)(r * LROW + 4 * (m >> 3) + 4 * q);

    float* const obw  = &ob[w][0];
    const int    cp   = 2 * (lane & 15);       // flush: group-local col pair
    const int    rr0  = lane >> 4;             // flush: row 0..3 (+4j)
    const size_t row0 = ((size_t)n * N_FILT + w * 16) * OUT_LEN;

    for (int gp = 0; gp < 32; ++gp) {          // 32 groups of 32 cols
        #pragma unroll
        for (int tl = 0; tl < 2; ++tl) {
            const int tt = gp * 2 + tl;
            float4v a0 = {0.f,0.f,0.f,0.f}, a1 = {0.f,0.f,0.f,0.f};
            const unsigned o0 = base + 8u * (unsigned)tt;
            #pragma unroll
            for (int kk = 0; kk < 4; ++kk) {   // kb = 2kk (a0), 2kk+1 (a1)
                a0 = __builtin_amdgcn_mfma_f32_16x16x32_f16(
                         __builtin_bit_cast(half8, Ah[2*kk]),
                         __builtin_bit_cast(half8, *(const uint4*)(&xf[o0 + 32*kk])),
                         a0, 0, 0, 0);
                a1 = __builtin_amdgcn_mfma_f32_16x16x32_f16(
                         __builtin_bit_cast(half8, Ah[2*kk+1]),
                         __builtin_bit_cast(half8, *(const uint4*)(&xf[o0 + 32*kk + 16])),
                         a1, 0, 0, 0);
            }
            const int oc = tl * 16 + m;        // group-local col
            #pragma unroll
            for (int rg = 0; rg < 4; ++rg)
                obw[(q * 4 + rg) * OBS2 + oc] = a0[rg] + a1[rg];
        }

        // flush group: 4 float2 stores (4 rows x 128 B each), conflict-free
        const int t0 = e0 + gp * 32 + cp;      // even; OUT_LEN even
        if (t0 + 1 < OUT_LEN) {
            #pragma unroll
            for (int j = 0; j < 4; ++j) {
                const int row = j * 4 + rr0;
                const float2v v = *(const float2v*)(&obw[row * OBS2 + cp]);
                *(float2v*)(out + row0 + (size_t)row * OUT_LEN + t0) = v;
            }
        }
    }
}

// ---------------------------------------------------------------------------
extern "C" void kernel_launch(void* const* d_in, const int* in_sizes, int n_in,
                              void* d_out, int out_size, void* d_ws, size_t ws_size,
                              hipStream_t stream)
{
    const float* x    = (const float*)d_in[0];
    const float* b1   = (const float*)d_in[1];
    const float* band = (const float*)d_in[2];
    float* outp = (float*)d_out;

    unsigned short* fh = (unsigned short*)d_ws;          // 80*256*2 B = 40 KB

    build_filters_kernel<<<dim3(N_FILT), dim3(256), 0, stream>>>(b1, band, fh);

    dim3 grid(1024);                                     // (strip, n) swizzled
    sinc_mfma_kernel<<<grid, dim3(TPB), 0, stream>>>(x, fh, outp);
}